// Round 6
// baseline (33074.750 us; speedup 1.0000x reference)
//
#include <hip/hip_runtime.h>

// Problem constants (fixed shapes from reference)
constexpr int S    = 4096;   // sequence length
constexpr int H    = 512;    // hidden
constexpr int G3   = 1536;   // 3*H
constexpr int NWG  = 32;     // scan worker workgroups
constexpr int GRID = 1024;   // launched WGs; ticket losers exit
constexpr int FAST_BUDGET = 20000;  // per-step fast-poll iters before sticky demotion
constexpr int WAIT_BUDGET = 2000;   // non-XCD0 ticket-counter poll budget

// HW_REG_XCC_ID: id=20, offset=0, size=32 (gfx940+). [learn_hip m09]
#define HWREG_XCC_ID (((32 - 1) << 11) | (0 << 6) | 20)

// Plain store: cached writeback in the issuing CU's XCD L2 (L1 write-through).
__device__ inline void st_plain_u64(void* p, unsigned long long v) {
    asm volatile("global_store_dwordx2 %0, %1, off" :: "v"(p), "v"(v) : "memory");
}
// sc0 load: bypass L1, read own-XCD L2 (hits dirty lines from same-XCD CUs).
__device__ inline uint4 ld4_sc0(const void* p) {
    uint4 v;
    asm volatile("global_load_dwordx4 %0, %1, off sc0\n\ts_waitcnt vmcnt(0)"
                 : "=v"(v) : "v"(p) : "memory");
    return v;
}
__device__ inline unsigned long long ld1_sc0_u64(const void* p) {
    unsigned long long v;
    asm volatile("global_load_dwordx2 %0, %1, off sc0\n\ts_waitcnt vmcnt(0)"
                 : "=v"(v) : "v"(p) : "memory");
    return v;
}
// LDS-only barrier: order ds ops, keep global stores in flight across it.
__device__ inline void barrier_lds() {
    __builtin_amdgcn_sched_barrier(0);
    asm volatile("s_waitcnt lgkmcnt(0)" ::: "memory");
    __builtin_amdgcn_s_barrier();
    __builtin_amdgcn_sched_barrier(0);
}

// ---------------------------------------------------------------------------
// Kernel A: gx[t][o] = b_ih[o] + sum_k emb[x[t]][k] * w_ih[o][k]
// (unchanged — passed with absmax 0.0; ~1% of runtime)
// ---------------------------------------------------------------------------
__global__ __launch_bounds__(256) void gemm_gx(
    const int* __restrict__ x, const float* __restrict__ emb,
    const float* __restrict__ w_ih, const float* __restrict__ b_ih,
    float* __restrict__ gx)
{
    __shared__ alignas(16) float As[128][36];
    __shared__ alignas(16) float Bs[32][132];

    const int tid  = threadIdx.x;
    const int row0 = (blockIdx.x / 12) * 128;
    const int col0 = (blockIdx.x % 12) * 128;
    const int tx   = tid & 15;
    const int ty   = tid >> 4;

    float acc[8][8] = {};

    for (int k0 = 0; k0 < H; k0 += 32) {
        #pragma unroll
        for (int p = 0; p < 4; ++p) {
            const int rl = (tid >> 3) + 32 * p;
            const int kk = (tid & 7) * 4;
            const int xi = x[row0 + rl];
            const float4 va = *reinterpret_cast<const float4*>(
                emb + (size_t)xi * H + k0 + kk);
            *reinterpret_cast<float4*>(&As[rl][kk]) = va;

            const float4 vb = *reinterpret_cast<const float4*>(
                w_ih + (size_t)(col0 + rl) * H + k0 + kk);
            Bs[kk + 0][rl] = vb.x; Bs[kk + 1][rl] = vb.y;
            Bs[kk + 2][rl] = vb.z; Bs[kk + 3][rl] = vb.w;
        }
        __syncthreads();

        #pragma unroll
        for (int kk = 0; kk < 32; ++kk) {
            float a[8], b[8];
            #pragma unroll
            for (int q = 0; q < 4; ++q) {
                a[q]     = As[ty * 4 + q][kk];
                a[4 + q] = As[ty * 4 + 64 + q][kk];
            }
            const float4 b0 = *reinterpret_cast<const float4*>(&Bs[kk][tx * 4]);
            const float4 b1 = *reinterpret_cast<const float4*>(&Bs[kk][tx * 4 + 64]);
            b[0]=b0.x; b[1]=b0.y; b[2]=b0.z; b[3]=b0.w;
            b[4]=b1.x; b[5]=b1.y; b[6]=b1.z; b[7]=b1.w;
            #pragma unroll
            for (int ri = 0; ri < 8; ++ri)
                #pragma unroll
                for (int ci = 0; ci < 8; ++ci)
                    acc[ri][ci] = fmaf(a[ri], b[ci], acc[ri][ci]);
        }
        __syncthreads();
    }

    float bi[8];
    #pragma unroll
    for (int q = 0; q < 4; ++q) {
        bi[q]     = b_ih[col0 + tx * 4 + q];
        bi[4 + q] = b_ih[col0 + tx * 4 + 64 + q];
    }
    #pragma unroll
    for (int ri = 0; ri < 8; ++ri) {
        const int rr = row0 + ty * 4 + (ri & 3) + ((ri >> 2) << 6);
        float4 o0, o1;
        o0.x = acc[ri][0] + bi[0]; o0.y = acc[ri][1] + bi[1];
        o0.z = acc[ri][2] + bi[2]; o0.w = acc[ri][3] + bi[3];
        o1.x = acc[ri][4] + bi[4]; o1.y = acc[ri][5] + bi[5];
        o1.z = acc[ri][6] + bi[6]; o1.w = acc[ri][7] + bi[7];
        *reinterpret_cast<float4*>(gx + (size_t)rr * G3 + col0 + tx * 4)      = o0;
        *reinterpret_cast<float4*>(gx + (size_t)rr * G3 + col0 + tx * 4 + 64) = o1;
    }
}

// ---------------------------------------------------------------------------
// Kernel B: persistent GRU scan.
//  - 32 winners via MALL ticket (XCD0 waves ticket first; others after seeing
//    the counter full, bounded => liveness; output depends only on slice id).
//  - Startup: winner zeroes its hl2 lines + stores magic (PLAIN stores -> its
//    own L2), drains, publishes meta|xcc via MALL atomic. All winners wait for
//    32 metas, then sc0-probe all 32 magics. fast := same-xcc && all magics
//    seen — validates the exact plain-store/sc0-load mechanism end-to-end.
//  - Scan: producers DUAL-publish (tag<<32|val): plain->hl2 (L2) and relaxed
//    agent atomic->hml (MALL, round-1/3-proven). Consumers poll hl2 via sc0
//    dwordx4 with sticky demotion to the hml atomic-pair poll. Consumption is
//    ALWAYS tag-gated: a wrong placement costs speed, never correctness.
//  - End: all winners verify all hml tags == S (=> nobody polls hl2 anymore),
//    then zero-purge every plain-stored line so later graph replays cannot
//    see stale tags/magics in any L2.
// ---------------------------------------------------------------------------
__global__ __launch_bounds__(256) void gru_scan(
    const float* __restrict__ gx,
    const float* __restrict__ w_hh,
    const float* __restrict__ b_hh,
    const float* __restrict__ dec_w,
    const float* __restrict__ dec_b,
    const float* __restrict__ target,
    unsigned long long* __restrict__ hl2,    // [2][H] fast (XCD-L2) tag|value
    unsigned long long* __restrict__ probe,  // [32]  placement-probe magics
    unsigned long long* __restrict__ hml,    // [2][H] proven (MALL) tag|value
    unsigned int* __restrict__ meta,         // [32]  0x100|xcc per winner
    int* __restrict__ ticket,                // winner ticket counter
    float* __restrict__ out)
{
    __shared__ alignas(16) float w_lds[3 * 16 * 512];  // 96 KB
    __shared__ alignas(16) float h_lds[H];
    __shared__ int s_slice;
    __shared__ int s_fast;

    const int tid = threadIdx.x;

    // ---- winner selection + placement probe (thread 0) ----
    if (tid == 0) {
        const unsigned xcc = __builtin_amdgcn_s_getreg(HWREG_XCC_ID) & 7u;
        int t;
        if (xcc == 0u) {
            t = atomicAdd(ticket, 1);
        } else {
            int it = 0;
            while (it < WAIT_BUDGET) {
                const int c = __hip_atomic_load(ticket, __ATOMIC_RELAXED,
                                                __HIP_MEMORY_SCOPE_AGENT);
                if (c >= NWG) break;
                ++it;
            }
            t = atomicAdd(ticket, 1);   // full (=> lose) or liveness claim
        }
        const int sl = (t < NWG) ? t : -1;
        s_slice = sl;
        s_fast  = 0;
        if (sl >= 0) {
            // purge-own + magic (plain stores -> this CU's XCD L2)
            #pragma unroll
            for (int j = 0; j < 16; ++j) {
                st_plain_u64(hl2 +       sl * 16 + j, 0ull);
                st_plain_u64(hl2 + 512 + sl * 16 + j, 0ull);
            }
            const unsigned long long magic =
                0xC0DE000000000000ull | (unsigned long long)(0x100 | sl);
            st_plain_u64(probe + sl, magic);
            asm volatile("s_waitcnt vmcnt(0)" ::: "memory");
            __hip_atomic_store(meta + sl, 0x100u | xcc,
                               __ATOMIC_RELAXED, __HIP_MEMORY_SCOPE_AGENT);
            // wait all 32 metas (MALL), gather xcc agreement
            unsigned long long have = 0ull;
            unsigned xref = 0xFFu; bool same = true;
            while (have != 0xFFFFFFFFull) {
                for (int w = 0; w < 32; ++w) {
                    if ((have >> w) & 1ull) continue;
                    const unsigned m = __hip_atomic_load(meta + w,
                        __ATOMIC_RELAXED, __HIP_MEMORY_SCOPE_AGENT);
                    if (m & 0x100u) {
                        have |= 1ull << w;
                        const unsigned xc = m & 0xFFu;
                        if (xref == 0xFFu) xref = xc;
                        else if (xc != xref) same = false;
                    }
                }
            }
            // probe: every winner's magic must be visible through OUR L2 path
            bool ok = same;
            if (ok) {
                for (int w = 0; w < 32; ++w) {
                    const unsigned long long exp =
                        0xC0DE000000000000ull | (unsigned long long)(0x100 | w);
                    if (ld1_sc0_u64(probe + w) != exp) { ok = false; break; }
                }
            }
            s_fast = ok ? 1 : 0;
        }
    }
    __syncthreads();
    const int k = s_slice;
    if (k < 0) return;
    bool slow = (s_fast == 0);   // per-thread, sticky

    const int l = tid & 15;      // lane within 16-lane group (column owner)
    const int g = tid >> 4;      // group id 0..15
    const int i = k * 16 + g;    // owned hidden index

    // ---- stage W_hh slice into LDS (as round 5; conflict-free measured) ----
    #pragma unroll
    for (int m = 0; m < 24; ++m) {
        const int p = tid + 256 * m;
        const int q = p >> 11;
        const int r = (p >> 7) & 15;
        const int c = p & 127;
        const float4 v = *reinterpret_cast<const float4*>(
            w_hh + ((size_t)q * H + k * 16 + r) * H + 4 * c);
        *reinterpret_cast<float4*>(&w_lds[((q * 16 + r) << 9) + 4 * c]) = v;
    }
    const float bhr = b_hh[i], bhz = b_hh[H + i], bhn = b_hh[2 * H + i];

    float gxr = 0.f, gxz = 0.f, gxn = 0.f;
    if (l == 0) { gxr = gx[i]; gxz = gx[H + i]; gxn = gx[2 * H + i]; }
    __syncthreads();

    const float* wr_ = &w_lds[((0 * 16 + g) << 9) + 4 * l];
    const float* wz_ = &w_lds[((1 * 16 + g) << 9) + 4 * l];
    const float* wn_ = &w_lds[((2 * 16 + g) << 9) + 4 * l];

    for (int s = 0; s < S; ++s) {
        // --- obtain h_s into LDS (thread owns slots 2tid, 2tid+1) ---
        if (s == 0) {
            h_lds[2 * tid] = 0.f; h_lds[2 * tid + 1] = 0.f;
        } else {
            const unsigned tg   = (unsigned)s;
            const size_t   boff = (size_t)(s & 1) * H;
            unsigned x0, x1;
            bool got = false;
            if (!slow) {
                const void* src = (const char*)(hl2 + boff) + 16 * (size_t)tid;
                uint4 v = ld4_sc0(src);
                int it = 0;
                while (!(v.y == tg && v.w == tg) && it < FAST_BUDGET) {
                    ++it; v = ld4_sc0(src);
                }
                if (v.y == tg && v.w == tg) { x0 = v.x; x1 = v.z; got = true; }
                else slow = true;            // sticky, never consume unverified
            }
            if (!got) {   // proven MALL path (rounds 1/3)
                unsigned long long* src = hml + boff;
                unsigned long long v0 = 0, v1 = 0;
                bool d0 = false, d1 = false;
                while (!(d0 && d1)) {
                    if (!d0) { v0 = __hip_atomic_load(src + 2 * tid,
                                   __ATOMIC_RELAXED, __HIP_MEMORY_SCOPE_AGENT);
                               d0 = (unsigned)(v0 >> 32) == tg; }
                    if (!d1) { v1 = __hip_atomic_load(src + 2 * tid + 1,
                                   __ATOMIC_RELAXED, __HIP_MEMORY_SCOPE_AGENT);
                               d1 = (unsigned)(v1 >> 32) == tg; }
                }
                x0 = (unsigned)v0; x1 = (unsigned)v1;
            }
            h_lds[2 * tid]     = __uint_as_float(x0);
            h_lds[2 * tid + 1] = __uint_as_float(x1);
        }
        barrier_lds();

        const float hp = h_lds[i];

        // --- three 512-dots: lane l covers cols 4l+64j; weights from LDS ---
        float ar = 0.f, az = 0.f, an = 0.f;
        #pragma unroll
        for (int j = 0; j < 8; ++j) {
            const float4 hv = *reinterpret_cast<const float4*>(&h_lds[64 * j + 4 * l]);
            const float4 a  = *reinterpret_cast<const float4*>(wr_ + 64 * j);
            const float4 b  = *reinterpret_cast<const float4*>(wz_ + 64 * j);
            const float4 c  = *reinterpret_cast<const float4*>(wn_ + 64 * j);
            ar = fmaf(a.x, hv.x, fmaf(a.y, hv.y, fmaf(a.z, hv.z, fmaf(a.w, hv.w, ar))));
            az = fmaf(b.x, hv.x, fmaf(b.y, hv.y, fmaf(b.z, hv.z, fmaf(b.w, hv.w, az))));
            an = fmaf(c.x, hv.x, fmaf(c.y, hv.y, fmaf(c.z, hv.z, fmaf(c.w, hv.w, an))));
        }
        #pragma unroll
        for (int m = 8; m >= 1; m >>= 1) {
            ar += __shfl_xor(ar, m);
            az += __shfl_xor(az, m);
            an += __shfl_xor(an, m);
        }

        if (l == 0) {
            const float r  = 1.f / (1.f + __expf(-(gxr + ar + bhr)));
            const float z  = 1.f / (1.f + __expf(-(gxz + az + bhz)));
            const float nn = tanhf(gxn + r * (an + bhn));
            const float hnew = (1.f - z) * nn + z * hp;
            const unsigned long long pv =
                ((unsigned long long)(unsigned)(s + 1) << 32) |
                (unsigned long long)__float_as_uint(hnew);
            const size_t dsts = (size_t)((s + 1) & 1) * H + i;
            st_plain_u64(hl2 + dsts, pv);                 // fast (own XCD L2)
            __hip_atomic_store(hml + dsts, pv,            // proven (MALL)
                               __ATOMIC_RELAXED, __HIP_MEMORY_SCOPE_AGENT);
            const int sn = (s + 1 < S) ? (s + 1) : s;     // gx prefetch
            gxr = gx[(size_t)sn * G3 + i];
            gxz = gx[(size_t)sn * G3 + H + i];
            gxn = gx[(size_t)sn * G3 + 2 * H + i];
        }
        barrier_lds();   // LDS-only: producer stores stay in flight
    }

    // ---- global completion: every thread waits its 2 hml slots == S.
    //      Collectively (x32 WGs) this proves all tags S stored => no WG will
    //      ever poll hl2 again => purge below is race-free. ----
    {
        const unsigned tg = (unsigned)S;   // buffer (S&1)==0
        unsigned long long v0 = 0, v1 = 0;
        bool d0 = false, d1 = false;
        while (!(d0 && d1)) {
            if (!d0) { v0 = __hip_atomic_load(hml + 2 * tid,
                           __ATOMIC_RELAXED, __HIP_MEMORY_SCOPE_AGENT);
                       d0 = (unsigned)(v0 >> 32) == tg; }
            if (!d1) { v1 = __hip_atomic_load(hml + 2 * tid + 1,
                           __ATOMIC_RELAXED, __HIP_MEMORY_SCOPE_AGENT);
                       d1 = (unsigned)(v1 >> 32) == tg; }
        }
        h_lds[2 * tid]     = __uint_as_float((unsigned)v0);
        h_lds[2 * tid + 1] = __uint_as_float((unsigned)v1);
    }
    __syncthreads();

    // epilogue: slice-0 WG computes BCE loss
    if (k == 0 && tid < 64) {
        float p = 0.f;
        #pragma unroll
        for (int j = 0; j < 8; ++j)
            p = fmaf(h_lds[tid + 64 * j], dec_w[tid + 64 * j], p);
        #pragma unroll
        for (int m = 32; m >= 1; m >>= 1) p += __shfl_xor(p, m);
        if (tid == 0) {
            const float xl = p + dec_b[0];
            const float t  = target[0];
            const float loss = fmaxf(xl, 0.f) - xl * t +
                               log1pf(__expf(-fabsf(xl)));
            out[0] = loss;
        }
    }

    // purge every line we plain-stored (zero tags/magic) so later replays
    // cannot see stale L2 ghosts; safe because all WGs finished (all-S above).
    if (tid == 0) {
        #pragma unroll
        for (int j = 0; j < 16; ++j) {
            st_plain_u64(hl2 +       k * 16 + j, 0ull);
            st_plain_u64(hl2 + 512 + k * 16 + j, 0ull);
        }
        st_plain_u64(probe + k, 0ull);
        asm volatile("s_waitcnt vmcnt(0)" ::: "memory");
    }
}

// ---------------------------------------------------------------------------
extern "C" void kernel_launch(void* const* d_in, const int* in_sizes, int n_in,
                              void* d_out, int out_size, void* d_ws, size_t ws_size,
                              hipStream_t stream) {
    const int*   x      = (const int*)d_in[0];
    const float* target = (const float*)d_in[1];
    const float* emb    = (const float*)d_in[2];
    const float* w_ih   = (const float*)d_in[3];
    const float* w_hh   = (const float*)d_in[4];
    const float* b_ih   = (const float*)d_in[5];
    const float* b_hh   = (const float*)d_in[6];
    const float* dec_w  = (const float*)d_in[7];
    const float* dec_b  = (const float*)d_in[8];
    float*       out    = (float*)d_out;

    float* gx = (float*)d_ws;                                   // [S][1536]
    unsigned long long* hl2 =
        (unsigned long long*)((char*)d_ws + (size_t)S * G3 * sizeof(float));
    unsigned long long* probe = hl2 + 2 * H;        // 32 u64
    unsigned long long* hml   = probe + 32;         // [2][H]
    unsigned int*       meta  = (unsigned int*)(hml + 2 * H);   // 32 u32
    int*                tick  = (int*)(meta + 32);

    // Clear all sync state every launch.
    const size_t sync_bytes =
        (2 * H + 32 + 2 * H) * sizeof(unsigned long long) + 32 * 4 + 64;
    hipMemsetAsync(hl2, 0, sync_bytes, stream);

    gemm_gx<<<dim3(32 * 12), dim3(256), 0, stream>>>(x, emb, w_ih, b_ih, gx);
    gru_scan<<<dim3(GRID), dim3(256), 0, stream>>>(gx, w_hh, b_hh, dec_w, dec_b,
                                                   target, hl2, probe, hml, meta,
                                                   tick, out);
}

// Round 7
// 7933.884 us; speedup vs baseline: 4.1688x; 4.1688x over previous
//
#include <hip/hip_runtime.h>

// Problem constants (fixed shapes from reference)
constexpr int S   = 4096;   // sequence length
constexpr int H   = 512;    // hidden
constexpr int G3  = 1536;   // 3*H
constexpr int NWG = 32;     // scan worker workgroups; each owns H/NWG = 16 hidden idx

// Single 16B poll load straight from the coherence point (sc0 = L1 bypass,
// sc1 = L2 bypass -> MALL). Covers BOTH of a thread's (tag|value) u64 slots in
// one instruction -> sampling period = 1 RTT instead of 2 serialized RTTs.
// Correctness of this exact instruction was proven in round 5 (passed).
__device__ inline uint4 ld4_mall(const void* p) {
    uint4 v;
    asm volatile("global_load_dwordx4 %0, %1, off sc0 sc1\n\ts_waitcnt vmcnt(0)"
                 : "=v"(v) : "v"(p) : "memory");
    return v;
}

// LDS-only barrier: order LDS ops across the workgroup WITHOUT draining vmcnt
// (the default __syncthreads emits s_waitcnt vmcnt(0) -> waits for the MALL
// store ACK every step, ~300-400ns pure loss). Pattern per m214 rule 18:
// memory-clobber asm + sched_barrier fences keep the compiler from moving
// LDS ops across.
__device__ inline void barrier_lds() {
    __builtin_amdgcn_sched_barrier(0);
    asm volatile("s_waitcnt lgkmcnt(0)" ::: "memory");
    __builtin_amdgcn_s_barrier();
    __builtin_amdgcn_sched_barrier(0);
}

// ---------------------------------------------------------------------------
// Kernel A: gx[t][o] = b_ih[o] + sum_k emb[x[t]][k] * w_ih[o][k]
// (unchanged — passed with absmax 0.0; ~1% of runtime)
// ---------------------------------------------------------------------------
__global__ __launch_bounds__(256) void gemm_gx(
    const int* __restrict__ x, const float* __restrict__ emb,
    const float* __restrict__ w_ih, const float* __restrict__ b_ih,
    float* __restrict__ gx)
{
    __shared__ alignas(16) float As[128][36];
    __shared__ alignas(16) float Bs[32][132];

    const int tid  = threadIdx.x;
    const int row0 = (blockIdx.x / 12) * 128;
    const int col0 = (blockIdx.x % 12) * 128;
    const int tx   = tid & 15;
    const int ty   = tid >> 4;

    float acc[8][8] = {};

    for (int k0 = 0; k0 < H; k0 += 32) {
        #pragma unroll
        for (int p = 0; p < 4; ++p) {
            const int rl = (tid >> 3) + 32 * p;
            const int kk = (tid & 7) * 4;
            const int xi = x[row0 + rl];
            const float4 va = *reinterpret_cast<const float4*>(
                emb + (size_t)xi * H + k0 + kk);
            *reinterpret_cast<float4*>(&As[rl][kk]) = va;

            const float4 vb = *reinterpret_cast<const float4*>(
                w_ih + (size_t)(col0 + rl) * H + k0 + kk);
            Bs[kk + 0][rl] = vb.x; Bs[kk + 1][rl] = vb.y;
            Bs[kk + 2][rl] = vb.z; Bs[kk + 3][rl] = vb.w;
        }
        __syncthreads();

        #pragma unroll
        for (int kk = 0; kk < 32; ++kk) {
            float a[8], b[8];
            #pragma unroll
            for (int q = 0; q < 4; ++q) {
                a[q]     = As[ty * 4 + q][kk];
                a[4 + q] = As[ty * 4 + 64 + q][kk];
            }
            const float4 b0 = *reinterpret_cast<const float4*>(&Bs[kk][tx * 4]);
            const float4 b1 = *reinterpret_cast<const float4*>(&Bs[kk][tx * 4 + 64]);
            b[0]=b0.x; b[1]=b0.y; b[2]=b0.z; b[3]=b0.w;
            b[4]=b1.x; b[5]=b1.y; b[6]=b1.z; b[7]=b1.w;
            #pragma unroll
            for (int ri = 0; ri < 8; ++ri)
                #pragma unroll
                for (int ci = 0; ci < 8; ++ci)
                    acc[ri][ci] = fmaf(a[ri], b[ci], acc[ri][ci]);
        }
        __syncthreads();
    }

    float bi[8];
    #pragma unroll
    for (int q = 0; q < 4; ++q) {
        bi[q]     = b_ih[col0 + tx * 4 + q];
        bi[4 + q] = b_ih[col0 + tx * 4 + 64 + q];
    }
    #pragma unroll
    for (int ri = 0; ri < 8; ++ri) {
        const int rr = row0 + ty * 4 + (ri & 3) + ((ri >> 2) << 6);
        float4 o0, o1;
        o0.x = acc[ri][0] + bi[0]; o0.y = acc[ri][1] + bi[1];
        o0.z = acc[ri][2] + bi[2]; o0.w = acc[ri][3] + bi[3];
        o1.x = acc[ri][4] + bi[4]; o1.y = acc[ri][5] + bi[5];
        o1.z = acc[ri][6] + bi[6]; o1.w = acc[ri][7] + bi[7];
        *reinterpret_cast<float4*>(gx + (size_t)rr * G3 + col0 + tx * 4)      = o0;
        *reinterpret_cast<float4*>(gx + (size_t)rr * G3 + col0 + tx * 4 + 64) = o1;
    }
}

// ---------------------------------------------------------------------------
// Kernel B: persistent GRU scan. 32 WGs x 256 threads.
// = ROUND 3 (proven, 8.09ms) with exactly two latency fixes:
//   (1) poll = ONE dwordx4 sc0 sc1 load per iteration (round-5-proven
//       instruction) instead of two serialized u64 atomic loads -> sampling
//       period 1 RTT instead of 2.
//   (2) in-loop barriers are LDS-only (lgkmcnt+s_barrier) -> the producer's
//       MALL store stays in flight across the barrier instead of stalling
//       every wave on its ack (default __syncthreads drains vmcnt(0)).
// Weight handling = round 3 (compiler remat from L2; measured FASTER than
// LDS staging: 8.47ms vs 9.37ms dispatch).
// ---------------------------------------------------------------------------
__global__ __launch_bounds__(256, 1) void gru_scan(
    const float* __restrict__ gx,
    const float* __restrict__ w_hh,
    const float* __restrict__ b_hh,
    const float* __restrict__ dec_w,
    const float* __restrict__ dec_b,
    const float* __restrict__ target,
    unsigned long long* __restrict__ hbuf,   // [2][H] (tag|value)
    float* __restrict__ out)
{
    __shared__ float h_lds[H];

    const int k   = blockIdx.x;
    const int tid = threadIdx.x;
    const int l   = tid & 15;    // lane within 16-lane group (column owner)
    const int g   = tid >> 4;    // group id 0..15
    const int i   = k * 16 + g;  // owned hidden index

    // Recurrent weights: rows i, H+i, 2H+i; cols 4l+64j+q. (Compiler chooses
    // to re-load these from L2 per step; measured faster than LDS staging.)
    float4 wr[8], wz[8], wn[8];
    #pragma unroll
    for (int j = 0; j < 8; ++j) {
        const int c = 4 * l + 64 * j;
        wr[j] = *reinterpret_cast<const float4*>(w_hh + (size_t)i * H + c);
        wz[j] = *reinterpret_cast<const float4*>(w_hh + (size_t)(H + i) * H + c);
        wn[j] = *reinterpret_cast<const float4*>(w_hh + (size_t)(2 * H + i) * H + c);
    }
    const float bhr = b_hh[i], bhz = b_hh[H + i], bhn = b_hh[2 * H + i];

    // gx prefetch regs (only lane 0 of each group uses them)
    float gxr = 0.f, gxz = 0.f, gxn = 0.f;
    if (l == 0) { gxr = gx[i]; gxz = gx[H + i]; gxn = gx[2 * H + i]; }

    const int e0 = 2 * tid, e1 = 2 * tid + 1;

    for (int s = 0; s < S; ++s) {
        // --- obtain h_s into LDS (thread owns slots 2tid, 2tid+1) ---
        if (s == 0) {
            h_lds[e0] = 0.f; h_lds[e1] = 0.f;   // h0 = zeros, no poll
        } else {
            const unsigned tg = (unsigned)s;
            const void* src =
                (const char*)(hbuf + (size_t)(s & 1) * H) + 16 * (size_t)tid;
            uint4 v = ld4_mall(src);
            while (!(v.y == tg && v.w == tg)) {
                v = ld4_mall(src);
            }
            h_lds[e0] = __uint_as_float(v.x);
            h_lds[e1] = __uint_as_float(v.z);
        }
        barrier_lds();

        const float hp = h_lds[i];

        // --- three 512-dots: lane l covers cols 4l+64j via ds_read_b128 ---
        float ar = 0.f, az = 0.f, an = 0.f;
        #pragma unroll
        for (int j = 0; j < 8; ++j) {
            const float4 hv =
                *reinterpret_cast<const float4*>(&h_lds[64 * j + 4 * l]);
            ar = fmaf(wr[j].x, hv.x, fmaf(wr[j].y, hv.y,
                 fmaf(wr[j].z, hv.z, fmaf(wr[j].w, hv.w, ar))));
            az = fmaf(wz[j].x, hv.x, fmaf(wz[j].y, hv.y,
                 fmaf(wz[j].z, hv.z, fmaf(wz[j].w, hv.w, az))));
            an = fmaf(wn[j].x, hv.x, fmaf(wn[j].y, hv.y,
                 fmaf(wn[j].z, hv.z, fmaf(wn[j].w, hv.w, an))));
        }
        #pragma unroll
        for (int m = 8; m >= 1; m >>= 1) {   // butterfly within 16-lane group
            ar += __shfl_xor(ar, m);
            az += __shfl_xor(az, m);
            an += __shfl_xor(an, m);
        }

        if (l == 0) {
            const float r  = 1.f / (1.f + __expf(-(gxr + ar + bhr)));
            const float z  = 1.f / (1.f + __expf(-(gxz + az + bhz)));
            const float nn = tanhf(gxn + r * (an + bhn));
            const float hnew = (1.f - z) * nn + z * hp;
            const unsigned long long pv =
                ((unsigned long long)(unsigned)(s + 1) << 32) |
                (unsigned long long)__float_as_uint(hnew);
            __hip_atomic_store(hbuf + (size_t)((s + 1) & 1) * H + i, pv,
                               __ATOMIC_RELAXED, __HIP_MEMORY_SCOPE_AGENT);
            // prefetch next step's gx slice (completes under next poll)
            const int sn = (s + 1 < S) ? (s + 1) : s;
            gxr = gx[(size_t)sn * G3 + i];
            gxz = gx[(size_t)sn * G3 + H + i];
            gxn = gx[(size_t)sn * G3 + 2 * H + i];
        }
        barrier_lds();   // LDS-only: producer store stays in flight
    }

    // --- epilogue: WG0 gathers h_S (tag S, buffer S&1 == 0) and computes BCE ---
    if (k == 0) {
        const unsigned tg = (unsigned)S;
        const void* src = (const char*)hbuf + 16 * (size_t)tid;
        uint4 v = ld4_mall(src);
        while (!(v.y == tg && v.w == tg)) {
            v = ld4_mall(src);
        }
        h_lds[e0] = __uint_as_float(v.x);
        h_lds[e1] = __uint_as_float(v.z);
        __syncthreads();

        if (tid < 64) {
            float p = 0.f;
            #pragma unroll
            for (int j = 0; j < 8; ++j)
                p = fmaf(h_lds[tid + 64 * j], dec_w[tid + 64 * j], p);
            #pragma unroll
            for (int m = 32; m >= 1; m >>= 1) p += __shfl_xor(p, m);
            if (tid == 0) {
                const float xl = p + dec_b[0];
                const float t  = target[0];
                const float loss = fmaxf(xl, 0.f) - xl * t +
                                   log1pf(__expf(-fabsf(xl)));
                out[0] = loss;
            }
        }
    }
}

// ---------------------------------------------------------------------------
extern "C" void kernel_launch(void* const* d_in, const int* in_sizes, int n_in,
                              void* d_out, int out_size, void* d_ws, size_t ws_size,
                              hipStream_t stream) {
    const int*   x      = (const int*)d_in[0];
    const float* target = (const float*)d_in[1];
    const float* emb    = (const float*)d_in[2];
    const float* w_ih   = (const float*)d_in[3];
    const float* w_hh   = (const float*)d_in[4];
    const float* b_ih   = (const float*)d_in[5];
    const float* b_hh   = (const float*)d_in[6];
    const float* dec_w  = (const float*)d_in[7];
    const float* dec_b  = (const float*)d_in[8];
    float*       out    = (float*)d_out;

    float* gx = (float*)d_ws;                                   // [S][1536] = 25.2 MB
    unsigned long long* hbuf =
        (unsigned long long*)((char*)d_ws + (size_t)S * G3 * sizeof(float)); // [2][H]

    // Clear tags every launch so graph replays can't match stale tags.
    hipMemsetAsync(hbuf, 0, 2 * H * sizeof(unsigned long long), stream);

    gemm_gx<<<dim3(32 * 12), dim3(256), 0, stream>>>(x, emb, w_ih, b_ih, gx);
    gru_scan<<<dim3(NWG), dim3(256), 0, stream>>>(gx, w_hh, b_hh, dec_w, dec_b,
                                                  target, hbuf, out);
}